// Round 5
// baseline (546.958 us; speedup 1.0000x reference)
//
#include <hip/hip_runtime.h>

#define NN 50000
#define NE 800000
#define F 128
#define NBLK ((NN + 255) / 256)   // 196 scan blocks

typedef __attribute__((ext_vector_type(4))) unsigned short ushort4_t;
typedef __attribute__((ext_vector_type(8))) unsigned short ushort8_t;
typedef __attribute__((ext_vector_type(8))) short bf16x8;
typedef __attribute__((ext_vector_type(4))) float f32x4;

#define MFMA16x16x32 __builtin_amdgcn_mfma_f32_16x16x32_bf16

__device__ __forceinline__ float b2f(unsigned short u) {
    return __uint_as_float((unsigned int)u << 16);
}
__device__ __forceinline__ unsigned short f2b(float f) {
    unsigned int u = __float_as_uint(f);
    return (unsigned short)((u + 0x7fffu + ((u >> 16) & 1u)) >> 16);
}

// ---------------------------------------------------------------------------
// dtype probe (sampled): 256 odd words zero <=> int64 layout.
// ---------------------------------------------------------------------------
__global__ void k_detect(const unsigned int* __restrict__ w, int* __restrict__ nz) {
    __shared__ int s;
    if (threadIdx.x == 0) s = 0;
    __syncthreads();
    if (w[2 * threadIdx.x + 1] != 0u) atomicAdd(&s, 1);
    __syncthreads();
    if (threadIdx.x == 0) *nz = s;
}

// normalize edge_index -> int32 src/dst, and histogram in-degree (cnt[dst]++)
__global__ void k_convert(const void* __restrict__ ei, const int* __restrict__ nz,
                          int* __restrict__ src, int* __restrict__ dst,
                          int* __restrict__ cnt) {
    int e = blockIdx.x * blockDim.x + threadIdx.x;
    if (e >= NE) return;
    int s, d;
    if (*nz == 0) {
        const long long* p = (const long long*)ei;
        s = (int)p[e];
        d = (int)p[NE + e];
    } else {
        const int* p = (const int*)ei;
        s = p[e];
        d = p[NE + e];
    }
    src[e] = s;
    dst[e] = d;
    atomicAdd(&cnt[d], 1);
}

// fp32 -> bf16 cast, float4/ushort4 per thread
__global__ void k_cast(const float* __restrict__ in, unsigned short* __restrict__ out,
                       int n4) {
    int i = blockIdx.x * blockDim.x + threadIdx.x;
    if (i >= n4) return;
    float4 v = ((const float4*)in)[i];
    ushort4_t o;
    o.x = f2b(v.x); o.y = f2b(v.y); o.z = f2b(v.z); o.w = f2b(v.w);
    ((ushort4_t*)out)[i] = o;
}

// ---------------------------------------------------------------------------
// Weight prep: transpose + bf16 hi/lo split.
// conv: Wt[n=0..127][k=0..255], k<128 from WA, k>=128 from WB (both [128][128])
// ---------------------------------------------------------------------------
__global__ void k_prepw_conv(const float* __restrict__ WA, const float* __restrict__ WB,
                             unsigned short* __restrict__ hi,
                             unsigned short* __restrict__ lo) {
    int i = blockIdx.x * 256 + threadIdx.x;
    if (i >= 128 * 256) return;
    int n = i >> 8, k = i & 255;
    float v = (k < 128) ? WA[(size_t)k * F + n] : WB[(size_t)(k - 128) * F + n];
    unsigned short h = f2b(v);
    hi[(size_t)n * 256 + k] = h;
    lo[(size_t)n * 256 + k] = f2b(v - b2f(h));
}

// cls: Wt[n=0..255][k=0..127]; n<128 -> Wc1[k][n] (Gs), n>=128 -> Wc1[128+k][n-128]
__global__ void k_prepw_cls(const float* __restrict__ Wc1,
                            unsigned short* __restrict__ hi,
                            unsigned short* __restrict__ lo) {
    int i = blockIdx.x * 256 + threadIdx.x;
    if (i >= 256 * 128) return;
    int n = i >> 7, k = i & 127;
    float v = (n < 128) ? Wc1[(size_t)k * F + n]
                        : Wc1[(size_t)(128 + k) * F + (n - 128)];
    unsigned short h = f2b(v);
    hi[(size_t)n * 128 + k] = h;
    lo[(size_t)n * 128 + k] = f2b(v - b2f(h));
}

// ---- exclusive scan of cnt[NN] -> rowptr[NN+1], plus working copy fill[]
__global__ void k_bsum(const int* __restrict__ cnt, int* __restrict__ bsum) {
    __shared__ int s[256];
    int i = blockIdx.x * 256 + threadIdx.x;
    s[threadIdx.x] = (i < NN) ? cnt[i] : 0;
    __syncthreads();
    for (int st = 128; st > 0; st >>= 1) {
        if (threadIdx.x < st) s[threadIdx.x] += s[threadIdx.x + st];
        __syncthreads();
    }
    if (threadIdx.x == 0) bsum[blockIdx.x] = s[0];
}

__global__ void k_bscan(const int* __restrict__ bsum, int* __restrict__ boff) {
    int acc = 0;
    for (int b = 0; b < NBLK; ++b) { boff[b] = acc; acc += bsum[b]; }
}

__global__ void k_scan2(const int* __restrict__ cnt, const int* __restrict__ boff,
                        int* __restrict__ rowptr, int* __restrict__ fill) {
    __shared__ int s[256];
    int i = blockIdx.x * 256 + threadIdx.x;
    int v = (i < NN) ? cnt[i] : 0;
    s[threadIdx.x] = v;
    __syncthreads();
    for (int st = 1; st < 256; st <<= 1) {
        int t = (threadIdx.x >= st) ? s[threadIdx.x - st] : 0;
        __syncthreads();
        s[threadIdx.x] += t;
        __syncthreads();
    }
    int excl = s[threadIdx.x] - v + boff[blockIdx.x];
    if (i < NN) { rowptr[i] = excl; fill[i] = excl; }
    if (i == NN - 1) rowptr[NN] = excl + v;
}

// counting-sort edges by dst: ssort[pos] = src[e]
__global__ void k_perm(const int* __restrict__ src, const int* __restrict__ dst,
                       int* __restrict__ fill, int* __restrict__ ssort) {
    int e = blockIdx.x * 256 + threadIdx.x;
    if (e >= NE) return;
    int pos = atomicAdd(&fill[dst[e]], 1);
    ssort[pos] = src[e];
}

// gather-reduce + mean over bf16 rows: 16 lanes/node, 8 ch/lane (16B loads)
__launch_bounds__(256)
__global__ void k_gather(const unsigned short* __restrict__ xin,
                         const int* __restrict__ rowptr,
                         const int* __restrict__ ssort, float* __restrict__ agg) {
    int n = blockIdx.x * 16 + (threadIdx.x >> 4);
    if (n >= NN) return;
    int c = (threadIdx.x & 15) << 3;
    int beg = rowptr[n], end = rowptr[n + 1];
    float acc[8] = {};
    for (int j = beg; j < end; ++j) {
        int s = ssort[j];
        ushort8_t v = *(const ushort8_t*)(xin + (size_t)s * F + c);
#pragma unroll
        for (int k = 0; k < 8; ++k) acc[k] += b2f(v[k]);
    }
    float sc = 1.0f / (float)max(end - beg, 1);
    float4 o0 = make_float4(acc[0] * sc, acc[1] * sc, acc[2] * sc, acc[3] * sc);
    float4 o1 = make_float4(acc[4] * sc, acc[5] * sc, acc[6] * sc, acc[7] * sc);
    *(float4*)(agg + (size_t)n * F + c) = o0;
    *(float4*)(agg + (size_t)n * F + c + 4) = o1;
}

// ---------------------------------------------------------------------------
// MFMA conv GEMM (bf16x3 split precision == fp32-equivalent):
//   C[m][n] = act( sum_{k<128} A1[m][k] Wt[n][k] + sum_{k>=128} A2[m][k-128] Wt[n][k] + b[n] )
// Computed transposed (Wt is the MFMA A-operand, data the B-operand) so both
// operands are contiguous 16B/lane loads. Block = 16 rows x 128 cols, 4 waves
// (wave w -> cols w*32..w*32+31). M = 50000 = 3125 * 16 exactly (no tail).
// ---------------------------------------------------------------------------
__device__ __forceinline__ void split8(const float* __restrict__ p, bf16x8& dh, bf16x8& dl) {
    float vv[8];
    *(f32x4*)&vv[0] = *(const f32x4*)p;
    *(f32x4*)&vv[4] = *(const f32x4*)(p + 4);
#pragma unroll
    for (int j = 0; j < 8; ++j) {
        unsigned short h = f2b(vv[j]);
        dh[j] = (short)h;
        dl[j] = (short)f2b(vv[j] - b2f(h));
    }
}

__launch_bounds__(256)
__global__ void k_mm_conv(const float* __restrict__ A1, const void* __restrict__ A2,
                          int a2bf,
                          const unsigned short* __restrict__ Whi,
                          const unsigned short* __restrict__ Wlo,
                          const float* __restrict__ bias,
                          float* __restrict__ Cf, unsigned short* __restrict__ Ch,
                          int relu) {
    int lane = threadIdx.x & 63;
    int wave = threadIdx.x >> 6;
    int lm = lane & 15, quad = lane >> 4;
    int m = blockIdx.x * 16 + lm;
    int n0 = wave * 32;

    const unsigned short* wh0 = Whi + (size_t)(n0 + lm) * 256;
    const unsigned short* wl0 = Wlo + (size_t)(n0 + lm) * 256;
    const unsigned short* wh1 = Whi + (size_t)(n0 + 16 + lm) * 256;
    const unsigned short* wl1 = Wlo + (size_t)(n0 + 16 + lm) * 256;
    const float* a1p = A1 + (size_t)m * F;

    f32x4 acc0 = {0.f, 0.f, 0.f, 0.f};
    f32x4 acc1 = {0.f, 0.f, 0.f, 0.f};

    // k = 0..127 : A1 (fp32, split)
#pragma unroll
    for (int kc = 0; kc < 4; ++kc) {
        int kb = kc * 32 + quad * 8;
        bf16x8 dh, dl;
        split8(a1p + kb, dh, dl);
        bf16x8 w0h = *(const bf16x8*)(wh0 + kb);
        bf16x8 w0l = *(const bf16x8*)(wl0 + kb);
        bf16x8 w1h = *(const bf16x8*)(wh1 + kb);
        bf16x8 w1l = *(const bf16x8*)(wl1 + kb);
        acc0 = MFMA16x16x32(w0h, dh, acc0, 0, 0, 0);
        acc0 = MFMA16x16x32(w0h, dl, acc0, 0, 0, 0);
        acc0 = MFMA16x16x32(w0l, dh, acc0, 0, 0, 0);
        acc1 = MFMA16x16x32(w1h, dh, acc1, 0, 0, 0);
        acc1 = MFMA16x16x32(w1h, dl, acc1, 0, 0, 0);
        acc1 = MFMA16x16x32(w1l, dh, acc1, 0, 0, 0);
    }

    // k = 128..255 : A2 (bf16 exact, or fp32 split)
    if (a2bf) {
        const unsigned short* a2p = (const unsigned short*)A2 + (size_t)m * F;
#pragma unroll
        for (int kc = 4; kc < 8; ++kc) {
            int kb = kc * 32 + quad * 8;
            ushort8_t u = *(const ushort8_t*)(a2p + kb - 128);
            bf16x8 dh;
#pragma unroll
            for (int j = 0; j < 8; ++j) dh[j] = (short)u[j];
            bf16x8 w0h = *(const bf16x8*)(wh0 + kb);
            bf16x8 w0l = *(const bf16x8*)(wl0 + kb);
            bf16x8 w1h = *(const bf16x8*)(wh1 + kb);
            bf16x8 w1l = *(const bf16x8*)(wl1 + kb);
            acc0 = MFMA16x16x32(w0h, dh, acc0, 0, 0, 0);
            acc0 = MFMA16x16x32(w0l, dh, acc0, 0, 0, 0);
            acc1 = MFMA16x16x32(w1h, dh, acc1, 0, 0, 0);
            acc1 = MFMA16x16x32(w1l, dh, acc1, 0, 0, 0);
        }
    } else {
        const float* a2p = (const float*)A2 + (size_t)m * F;
#pragma unroll
        for (int kc = 4; kc < 8; ++kc) {
            int kb = kc * 32 + quad * 8;
            bf16x8 dh, dl;
            split8(a2p + kb - 128, dh, dl);
            bf16x8 w0h = *(const bf16x8*)(wh0 + kb);
            bf16x8 w0l = *(const bf16x8*)(wl0 + kb);
            bf16x8 w1h = *(const bf16x8*)(wh1 + kb);
            bf16x8 w1l = *(const bf16x8*)(wl1 + kb);
            acc0 = MFMA16x16x32(w0h, dh, acc0, 0, 0, 0);
            acc0 = MFMA16x16x32(w0h, dl, acc0, 0, 0, 0);
            acc0 = MFMA16x16x32(w0l, dh, acc0, 0, 0, 0);
            acc1 = MFMA16x16x32(w1h, dh, acc1, 0, 0, 0);
            acc1 = MFMA16x16x32(w1h, dl, acc1, 0, 0, 0);
            acc1 = MFMA16x16x32(w1l, dh, acc1, 0, 0, 0);
        }
    }

    // epilogue: D[n_local = quad*4+r][m_local = lm] -> C[m][n0(+16) + quad*4 + r]
    int nc0 = n0 + quad * 4;
    int nc1 = n0 + 16 + quad * 4;
    f32x4 b0 = {0.f, 0.f, 0.f, 0.f}, b1 = {0.f, 0.f, 0.f, 0.f};
    if (bias) {
        b0 = *(const f32x4*)(bias + nc0);
        b1 = *(const f32x4*)(bias + nc1);
    }
    float o0[4], o1[4];
#pragma unroll
    for (int r = 0; r < 4; ++r) {
        o0[r] = acc0[r] + b0[r];
        o1[r] = acc1[r] + b1[r];
        if (relu) { o0[r] = fmaxf(o0[r], 0.f); o1[r] = fmaxf(o1[r], 0.f); }
    }
    if (Cf) {
        *(f32x4*)(Cf + (size_t)m * F + nc0) = *(f32x4*)o0;
        *(f32x4*)(Cf + (size_t)m * F + nc1) = *(f32x4*)o1;
    }
    if (Ch) {
        ushort4_t u0, u1;
#pragma unroll
        for (int r = 0; r < 4; ++r) { u0[r] = f2b(o0[r]); u1[r] = f2b(o1[r]); }
        *(ushort4_t*)(Ch + (size_t)m * F + nc0) = u0;
        *(ushort4_t*)(Ch + (size_t)m * F + nc1) = u1;
    }
}

// ---------------------------------------------------------------------------
// MFMA classifier GEMM: [Gs|Gd] = h2 @ Wc1[0:256] as one K=128, N=256 GEMM.
// Block = 16 rows x 256 cols; wave w -> cols w*64..w*64+63 (4 n-tiles).
// ---------------------------------------------------------------------------
__launch_bounds__(256)
__global__ void k_mm_cls(const float* __restrict__ A,
                         const unsigned short* __restrict__ Whi,
                         const unsigned short* __restrict__ Wlo,
                         unsigned short* __restrict__ Gs,
                         unsigned short* __restrict__ Gd) {
    int lane = threadIdx.x & 63;
    int wave = threadIdx.x >> 6;
    int lm = lane & 15, quad = lane >> 4;
    int m = blockIdx.x * 16 + lm;
    int n0 = wave * 64;

    const float* ap = A + (size_t)m * F;
    const unsigned short* whp[4];
    const unsigned short* wlp[4];
#pragma unroll
    for (int nt = 0; nt < 4; ++nt) {
        whp[nt] = Whi + (size_t)(n0 + nt * 16 + lm) * 128;
        wlp[nt] = Wlo + (size_t)(n0 + nt * 16 + lm) * 128;
    }

    f32x4 acc[4] = {{0.f,0.f,0.f,0.f},{0.f,0.f,0.f,0.f},{0.f,0.f,0.f,0.f},{0.f,0.f,0.f,0.f}};

#pragma unroll
    for (int kc = 0; kc < 4; ++kc) {
        int kb = kc * 32 + quad * 8;
        bf16x8 dh, dl;
        split8(ap + kb, dh, dl);
#pragma unroll
        for (int nt = 0; nt < 4; ++nt) {
            bf16x8 wh = *(const bf16x8*)(whp[nt] + kb);
            bf16x8 wl = *(const bf16x8*)(wlp[nt] + kb);
            acc[nt] = MFMA16x16x32(wh, dh, acc[nt], 0, 0, 0);
            acc[nt] = MFMA16x16x32(wh, dl, acc[nt], 0, 0, 0);
            acc[nt] = MFMA16x16x32(wl, dh, acc[nt], 0, 0, 0);
        }
    }

#pragma unroll
    for (int nt = 0; nt < 4; ++nt) {
        int n = n0 + nt * 16 + quad * 4;
        ushort4_t u;
#pragma unroll
        for (int r = 0; r < 4; ++r) u[r] = f2b(acc[nt][r]);
        if (n < 128) *(ushort4_t*)(Gs + (size_t)m * F + n) = u;
        else         *(ushort4_t*)(Gd + (size_t)m * F + (n - 128)) = u;
    }
}

// ---------------------------------------------------------------------------
// edge classifier: grid-stride, 16 lanes/edge, 8 ch/lane (16B bf16 loads).
// ---------------------------------------------------------------------------
__launch_bounds__(256)
__global__ void k_edge(const unsigned short* __restrict__ Gs,
                       const unsigned short* __restrict__ Gd,
                       const float* __restrict__ ea, const int* __restrict__ src,
                       const int* __restrict__ dst, const float* __restrict__ Wc1e,
                       const float* __restrict__ bc1, const float* __restrict__ Wc2,
                       const float* __restrict__ bc2, float* __restrict__ out) {
    int lane = threadIdx.x & 15;
    int c = lane << 3;
    float w0[8], w1[8], w2[8], bb[8], wc[8];
#pragma unroll
    for (int k = 0; k < 8; ++k) {
        w0[k] = Wc1e[0 * F + c + k];
        w1[k] = Wc1e[1 * F + c + k];
        w2[k] = Wc1e[2 * F + c + k];
        bb[k] = bc1[c + k];
        wc[k] = Wc2[c + k];
    }
    float bout = bc2[0];

    int grp = (blockIdx.x * blockDim.x + threadIdx.x) >> 4;
    int ngrp = (gridDim.x * blockDim.x) >> 4;

    for (int e = grp; e < NE; e += ngrp) {
        int s = src[e], d = dst[e];
        ushort8_t gs = *(const ushort8_t*)(Gs + (size_t)s * F + c);
        ushort8_t gd = *(const ushort8_t*)(Gd + (size_t)d * F + c);
        float e0 = ea[(size_t)e * 3 + 0];
        float e1 = ea[(size_t)e * 3 + 1];
        float e2 = ea[(size_t)e * 3 + 2];

        float p = 0.f;
#pragma unroll
        for (int k = 0; k < 8; ++k) {
            float h = b2f(gs[k]) + b2f(gd[k]) + e0 * w0[k] + e1 * w1[k] + e2 * w2[k] + bb[k];
            h = fmaxf(h, 0.f);
            p += h * wc[k];
        }
#pragma unroll
        for (int off = 8; off > 0; off >>= 1) p += __shfl_down(p, off, 16);
        if (lane == 0) out[e] = p + bout;
    }
}

// ---------------------------------------------------------------------------
extern "C" void kernel_launch(void* const* d_in, const int* in_sizes, int n_in,
                              void* d_out, int out_size, void* d_ws, size_t ws_size,
                              hipStream_t stream) {
    const float* x    = (const float*)d_in[0];
    const void*  ei   = d_in[1];
    const float* ea   = (const float*)d_in[2];
    const float* W1l  = (const float*)d_in[3];
    const float* b1l  = (const float*)d_in[4];
    const float* W1r  = (const float*)d_in[5];
    const float* W2l  = (const float*)d_in[6];
    const float* b2l  = (const float*)d_in[7];
    const float* W2r  = (const float*)d_in[8];
    const float* Wc1  = (const float*)d_in[9];
    const float* bc1  = (const float*)d_in[10];
    const float* Wc2  = (const float*)d_in[11];
    const float* bc2  = (const float*)d_in[12];
    float* out = (float*)d_out;

    char* w = (char*)d_ws;
    int* flag   = (int*)w;          w += 256;
    int* bsum   = (int*)w;          w += 1024;
    int* boff   = (int*)w;          w += 1024;
    int* src    = (int*)w;          w += (size_t)NE * 4;
    int* dst    = (int*)w;          w += (size_t)NE * 4;
    int* ssort  = (int*)w;          w += (size_t)NE * 4;
    int* cnt    = (int*)w;          w += (size_t)NN * 4;
    int* rowptr = (int*)w;          w += (size_t)(NN + 1) * 4;
    int* fill   = (int*)w;          w += (size_t)NN * 4;
    w = (char*)(((size_t)w + 255) & ~(size_t)255);
    unsigned short* w1hi = (unsigned short*)w;  w += 128 * 256 * 2;
    unsigned short* w1lo = (unsigned short*)w;  w += 128 * 256 * 2;
    unsigned short* w2hi = (unsigned short*)w;  w += 128 * 256 * 2;
    unsigned short* w2lo = (unsigned short*)w;  w += 128 * 256 * 2;
    unsigned short* wchi = (unsigned short*)w;  w += 256 * 128 * 2;
    unsigned short* wclo = (unsigned short*)w;  w += 256 * 128 * 2;
    float* B0 = (float*)w;              w += (size_t)NN * F * 4;  // agg1, agg2, h2
    unsigned short* xh  = (unsigned short*)w;  w += (size_t)NN * F * 2;
    unsigned short* h1h = (unsigned short*)w;  w += (size_t)NN * F * 2;
    unsigned short* Gsh = (unsigned short*)w;  w += (size_t)NN * F * 2;
    unsigned short* Gdh = (unsigned short*)w;  w += (size_t)NN * F * 2;

    hipMemsetAsync(cnt, 0, (size_t)NN * 4, stream);

    // edge-index normalization + degree histogram + casts + weight prep
    k_detect<<<1, 256, 0, stream>>>((const unsigned int*)ei, flag);
    k_convert<<<(NE + 255) / 256, 256, 0, stream>>>(ei, flag, src, dst, cnt);
    k_cast<<<(NN * F / 4 + 255) / 256, 256, 0, stream>>>(x, xh, NN * F / 4);
    k_prepw_conv<<<128, 256, 0, stream>>>(W1l, W1r, w1hi, w1lo);
    k_prepw_conv<<<128, 256, 0, stream>>>(W2l, W2r, w2hi, w2lo);
    k_prepw_cls<<<128, 256, 0, stream>>>(Wc1, wchi, wclo);

    // CSR build
    k_bsum<<<NBLK, 256, 0, stream>>>(cnt, bsum);
    k_bscan<<<1, 1, 0, stream>>>(bsum, boff);
    k_scan2<<<NBLK, 256, 0, stream>>>(cnt, boff, rowptr, fill);
    k_perm<<<(NE + 255) / 256, 256, 0, stream>>>(src, dst, fill, ssort);

    int mmblocks = NN / 16;            // 3125, exact
    int agblocks = (NN + 15) / 16;

    // conv1: agg1 = mean-gather(xh); h1 (bf16) = relu(agg1@W1l + x@W1r + b1l)
    k_gather<<<agblocks, 256, 0, stream>>>(xh, rowptr, ssort, B0);
    k_mm_conv<<<mmblocks, 256, 0, stream>>>(B0, x, 0, w1hi, w1lo, b1l,
                                            nullptr, h1h, 1);

    // conv2: agg2 = mean-gather(h1h); h2 (fp32, in-place B0) = agg2@W2l + h1@W2r + b2l
    k_gather<<<agblocks, 256, 0, stream>>>(h1h, rowptr, ssort, B0);
    k_mm_conv<<<mmblocks, 256, 0, stream>>>(B0, h1h, 1, w2hi, w2lo, b2l,
                                            B0, nullptr, 0);

    // classifier node-side precompute: [Gs|Gd] = h2 @ Wc1[0:256]
    k_mm_cls<<<mmblocks, 256, 0, stream>>>(B0, wchi, wclo, Gsh, Gdh);

    // edge pass: 16 lanes per edge
    k_edge<<<4096, 256, 0, stream>>>(Gsh, Gdh, ea, src, dst,
                                     Wc1 + 256 * F, bc1, Wc2, bc2, out);
}

// Round 6
// 427.664 us; speedup vs baseline: 1.2789x; 1.2789x over previous
//
#include <hip/hip_runtime.h>

#define NN 50000
#define NE 800000
#define F 128
#define NBLK ((NN + 255) / 256)   // 196 scan blocks
#define NMT (NN / 16)             // 3125 m-tiles, exact

typedef __attribute__((ext_vector_type(4))) unsigned short ushort4_t;
typedef __attribute__((ext_vector_type(8))) unsigned short ushort8_t;
typedef __attribute__((ext_vector_type(8))) short bf16x8;
typedef __attribute__((ext_vector_type(4))) float f32x4;

#define MFMA16x16x32 __builtin_amdgcn_mfma_f32_16x16x32_bf16

__device__ __forceinline__ float b2f(unsigned short u) {
    return __uint_as_float((unsigned int)u << 16);
}
__device__ __forceinline__ unsigned short f2b(float f) {
    unsigned int u = __float_as_uint(f);
    return (unsigned short)((u + 0x7fffu + ((u >> 16) & 1u)) >> 16);
}

// ---------------------------------------------------------------------------
// dtype probe (sampled): 256 odd words zero <=> int64 layout.
// ---------------------------------------------------------------------------
__global__ void k_detect(const unsigned int* __restrict__ w, int* __restrict__ nz) {
    __shared__ int s;
    if (threadIdx.x == 0) s = 0;
    __syncthreads();
    if (w[2 * threadIdx.x + 1] != 0u) atomicAdd(&s, 1);
    __syncthreads();
    if (threadIdx.x == 0) *nz = s;
}

// normalize edge_index -> int32 src/dst, and histogram in-degree (cnt[dst]++)
__global__ void k_convert(const void* __restrict__ ei, const int* __restrict__ nz,
                          int* __restrict__ src, int* __restrict__ dst,
                          int* __restrict__ cnt) {
    int e = blockIdx.x * blockDim.x + threadIdx.x;
    if (e >= NE) return;
    int s, d;
    if (*nz == 0) {
        const long long* p = (const long long*)ei;
        s = (int)p[e];
        d = (int)p[NE + e];
    } else {
        const int* p = (const int*)ei;
        s = p[e];
        d = p[NE + e];
    }
    src[e] = s;
    dst[e] = d;
    atomicAdd(&cnt[d], 1);
}

// fp32 -> bf16 cast, float4/ushort4 per thread
__global__ void k_cast(const float* __restrict__ in, unsigned short* __restrict__ out,
                       int n4) {
    int i = blockIdx.x * blockDim.x + threadIdx.x;
    if (i >= n4) return;
    float4 v = ((const float4*)in)[i];
    ushort4_t o;
    o.x = f2b(v.x); o.y = f2b(v.y); o.z = f2b(v.z); o.w = f2b(v.w);
    ((ushort4_t*)out)[i] = o;
}

// ---------------------------------------------------------------------------
// Weight prep: transpose + bf16 hi/lo split (W stays exact as hi+lo).
// conv: Wt[n=0..127][k=0..255], k<128 from WA, k>=128 from WB (both [128][128])
// ---------------------------------------------------------------------------
__global__ void k_prepw_conv(const float* __restrict__ WA, const float* __restrict__ WB,
                             unsigned short* __restrict__ hi,
                             unsigned short* __restrict__ lo) {
    int i = blockIdx.x * 256 + threadIdx.x;
    if (i >= 128 * 256) return;
    int n = i >> 8, k = i & 255;
    float v = (k < 128) ? WA[(size_t)k * F + n] : WB[(size_t)(k - 128) * F + n];
    unsigned short h = f2b(v);
    hi[(size_t)n * 256 + k] = h;
    lo[(size_t)n * 256 + k] = f2b(v - b2f(h));
}

// cls: Wt[n=0..255][k=0..127]; n<128 -> Wc1[k][n] (Gs), n>=128 -> Wc1[128+k][n-128]
__global__ void k_prepw_cls(const float* __restrict__ Wc1,
                            unsigned short* __restrict__ hi,
                            unsigned short* __restrict__ lo) {
    int i = blockIdx.x * 256 + threadIdx.x;
    if (i >= 256 * 128) return;
    int n = i >> 7, k = i & 127;
    float v = (n < 128) ? Wc1[(size_t)k * F + n]
                        : Wc1[(size_t)(128 + k) * F + (n - 128)];
    unsigned short h = f2b(v);
    hi[(size_t)n * 128 + k] = h;
    lo[(size_t)n * 128 + k] = f2b(v - b2f(h));
}

// ---- exclusive scan of cnt[NN] -> rowptr[NN+1], plus working copy fill[]
__global__ void k_bsum(const int* __restrict__ cnt, int* __restrict__ bsum) {
    __shared__ int s[256];
    int i = blockIdx.x * 256 + threadIdx.x;
    s[threadIdx.x] = (i < NN) ? cnt[i] : 0;
    __syncthreads();
    for (int st = 128; st > 0; st >>= 1) {
        if (threadIdx.x < st) s[threadIdx.x] += s[threadIdx.x + st];
        __syncthreads();
    }
    if (threadIdx.x == 0) bsum[blockIdx.x] = s[0];
}

__global__ void k_bscan(const int* __restrict__ bsum, int* __restrict__ boff) {
    int acc = 0;
    for (int b = 0; b < NBLK; ++b) { boff[b] = acc; acc += bsum[b]; }
}

__global__ void k_scan2(const int* __restrict__ cnt, const int* __restrict__ boff,
                        int* __restrict__ rowptr, int* __restrict__ fill) {
    __shared__ int s[256];
    int i = blockIdx.x * 256 + threadIdx.x;
    int v = (i < NN) ? cnt[i] : 0;
    s[threadIdx.x] = v;
    __syncthreads();
    for (int st = 1; st < 256; st <<= 1) {
        int t = (threadIdx.x >= st) ? s[threadIdx.x - st] : 0;
        __syncthreads();
        s[threadIdx.x] += t;
        __syncthreads();
    }
    int excl = s[threadIdx.x] - v + boff[blockIdx.x];
    if (i < NN) { rowptr[i] = excl; fill[i] = excl; }
    if (i == NN - 1) rowptr[NN] = excl + v;
}

// counting-sort edges by dst: ssort[pos] = src[e]
__global__ void k_perm(const int* __restrict__ src, const int* __restrict__ dst,
                       int* __restrict__ fill, int* __restrict__ ssort) {
    int e = blockIdx.x * 256 + threadIdx.x;
    if (e >= NE) return;
    int pos = atomicAdd(&fill[dst[e]], 1);
    ssort[pos] = src[e];
}

// gather-reduce + mean over bf16 rows -> bf16 out. 16 lanes/node, 8 ch/lane.
__launch_bounds__(256)
__global__ void k_gather(const unsigned short* __restrict__ xin,
                         const int* __restrict__ rowptr,
                         const int* __restrict__ ssort,
                         unsigned short* __restrict__ agg) {
    int n = blockIdx.x * 16 + (threadIdx.x >> 4);
    if (n >= NN) return;
    int c = (threadIdx.x & 15) << 3;
    int beg = rowptr[n], end = rowptr[n + 1];
    float acc[8] = {};
    for (int j = beg; j < end; ++j) {
        int s = ssort[j];
        ushort8_t v = *(const ushort8_t*)(xin + (size_t)s * F + c);
#pragma unroll
        for (int k = 0; k < 8; ++k) acc[k] += b2f(v[k]);
    }
    float sc = 1.0f / (float)max(end - beg, 1);
    ushort8_t o;
#pragma unroll
    for (int k = 0; k < 8; ++k) o[k] = f2b(acc[k] * sc);
    *(ushort8_t*)(agg + (size_t)n * F + c) = o;
}

// ---------------------------------------------------------------------------
// Conv GEMM, W-in-registers: C[m][n] = act(A1[m][0:128].Wt[n][0:128]
//                                        + A2[m][0:128].Wt[n][128:256] + b[n])
// A1/A2 bf16; W exact as bf16 hi+lo (2 MFMAs, dual acc chains).
// Wave = 1 n-tile (16 cols), strided m-loop; W fragments loaded once.
// ---------------------------------------------------------------------------
__launch_bounds__(256)
__global__ void k_mm_conv(const unsigned short* __restrict__ A1,
                          const unsigned short* __restrict__ A2,
                          const unsigned short* __restrict__ Whi,
                          const unsigned short* __restrict__ Wlo,
                          const float* __restrict__ bias,
                          unsigned short* __restrict__ Ch,
                          int relu, int nstripes) {
    int lane = threadIdx.x & 63;
    int wid = (blockIdx.x * 256 + threadIdx.x) >> 6;
    int ntile = wid & 7;          // 8 n-tiles cover N=128
    int stripe = wid >> 3;
    int lm = lane & 15, quad = lane >> 4;

    const unsigned short* whp = Whi + (size_t)(ntile * 16 + lm) * 256 + quad * 8;
    const unsigned short* wlp = Wlo + (size_t)(ntile * 16 + lm) * 256 + quad * 8;
    bf16x8 wh[8], wl[8];
#pragma unroll
    for (int kc = 0; kc < 8; ++kc) {
        wh[kc] = *(const bf16x8*)(whp + kc * 32);
        wl[kc] = *(const bf16x8*)(wlp + kc * 32);
    }
    int nc = ntile * 16 + quad * 4;
    f32x4 bfrag = *(const f32x4*)(bias + nc);

    for (int mt = stripe; mt < NMT; mt += nstripes) {
        int m = mt * 16 + lm;
        const unsigned short* a1p = A1 + (size_t)m * F + quad * 8;
        const unsigned short* a2p = A2 + (size_t)m * F + quad * 8;
        f32x4 accH = {0.f, 0.f, 0.f, 0.f};
        f32x4 accL = {0.f, 0.f, 0.f, 0.f};
#pragma unroll
        for (int kc = 0; kc < 4; ++kc) {
            bf16x8 d = *(const bf16x8*)(a1p + kc * 32);
            accH = MFMA16x16x32(wh[kc], d, accH, 0, 0, 0);
            accL = MFMA16x16x32(wl[kc], d, accL, 0, 0, 0);
        }
#pragma unroll
        for (int kc = 0; kc < 4; ++kc) {
            bf16x8 d = *(const bf16x8*)(a2p + kc * 32);
            accH = MFMA16x16x32(wh[4 + kc], d, accH, 0, 0, 0);
            accL = MFMA16x16x32(wl[4 + kc], d, accL, 0, 0, 0);
        }
        // D[n_local=quad*4+r][m_local=lm] -> C[mt*16+lm][ntile*16+quad*4+r]
        ushort4_t u;
#pragma unroll
        for (int r = 0; r < 4; ++r) {
            float o = accH[r] + accL[r] + bfrag[r];
            if (relu) o = fmaxf(o, 0.f);
            u[r] = f2b(o);
        }
        *(ushort4_t*)(Ch + (size_t)m * F + nc) = u;
    }
}

// ---------------------------------------------------------------------------
// Classifier GEMM: [Gs|Gd] = h2 @ Wc1[0:256]; K=128, N=256.
// Wave = n-tile pair {p, p+8}: tile p -> Gs cols p*16.., tile p+8 -> Gd.
// ---------------------------------------------------------------------------
__launch_bounds__(256)
__global__ void k_mm_cls(const unsigned short* __restrict__ A,
                         const unsigned short* __restrict__ Whi,
                         const unsigned short* __restrict__ Wlo,
                         unsigned short* __restrict__ Gs,
                         unsigned short* __restrict__ Gd, int nstripes) {
    int lane = threadIdx.x & 63;
    int wid = (blockIdx.x * 256 + threadIdx.x) >> 6;
    int p = wid & 7;
    int stripe = wid >> 3;
    int lm = lane & 15, quad = lane >> 4;

    const unsigned short* wh0p = Whi + (size_t)(p * 16 + lm) * 128 + quad * 8;
    const unsigned short* wl0p = Wlo + (size_t)(p * 16 + lm) * 128 + quad * 8;
    const unsigned short* wh1p = Whi + (size_t)((p + 8) * 16 + lm) * 128 + quad * 8;
    const unsigned short* wl1p = Wlo + (size_t)((p + 8) * 16 + lm) * 128 + quad * 8;
    bf16x8 wh0[4], wl0[4], wh1[4], wl1[4];
#pragma unroll
    for (int kc = 0; kc < 4; ++kc) {
        wh0[kc] = *(const bf16x8*)(wh0p + kc * 32);
        wl0[kc] = *(const bf16x8*)(wl0p + kc * 32);
        wh1[kc] = *(const bf16x8*)(wh1p + kc * 32);
        wl1[kc] = *(const bf16x8*)(wl1p + kc * 32);
    }
    int nc = p * 16 + quad * 4;

    for (int mt = stripe; mt < NMT; mt += nstripes) {
        int m = mt * 16 + lm;
        const unsigned short* ap = A + (size_t)m * F + quad * 8;
        f32x4 a0H = {0.f,0.f,0.f,0.f}, a0L = {0.f,0.f,0.f,0.f};
        f32x4 a1H = {0.f,0.f,0.f,0.f}, a1L = {0.f,0.f,0.f,0.f};
#pragma unroll
        for (int kc = 0; kc < 4; ++kc) {
            bf16x8 d = *(const bf16x8*)(ap + kc * 32);
            a0H = MFMA16x16x32(wh0[kc], d, a0H, 0, 0, 0);
            a0L = MFMA16x16x32(wl0[kc], d, a0L, 0, 0, 0);
            a1H = MFMA16x16x32(wh1[kc], d, a1H, 0, 0, 0);
            a1L = MFMA16x16x32(wl1[kc], d, a1L, 0, 0, 0);
        }
        ushort4_t u0, u1;
#pragma unroll
        for (int r = 0; r < 4; ++r) {
            u0[r] = f2b(a0H[r] + a0L[r]);
            u1[r] = f2b(a1H[r] + a1L[r]);
        }
        *(ushort4_t*)(Gs + (size_t)m * F + nc) = u0;
        *(ushort4_t*)(Gd + (size_t)m * F + nc) = u1;
    }
}

// ---------------------------------------------------------------------------
// edge classifier: grid-stride, 16 lanes/edge, 8 ch/lane (16B bf16 loads).
// ---------------------------------------------------------------------------
__launch_bounds__(256)
__global__ void k_edge(const unsigned short* __restrict__ Gs,
                       const unsigned short* __restrict__ Gd,
                       const float* __restrict__ ea, const int* __restrict__ src,
                       const int* __restrict__ dst, const float* __restrict__ Wc1e,
                       const float* __restrict__ bc1, const float* __restrict__ Wc2,
                       const float* __restrict__ bc2, float* __restrict__ out) {
    int lane = threadIdx.x & 15;
    int c = lane << 3;
    float w0[8], w1[8], w2[8], bb[8], wc[8];
#pragma unroll
    for (int k = 0; k < 8; ++k) {
        w0[k] = Wc1e[0 * F + c + k];
        w1[k] = Wc1e[1 * F + c + k];
        w2[k] = Wc1e[2 * F + c + k];
        bb[k] = bc1[c + k];
        wc[k] = Wc2[c + k];
    }
    float bout = bc2[0];

    int grp = (blockIdx.x * blockDim.x + threadIdx.x) >> 4;
    int ngrp = (gridDim.x * blockDim.x) >> 4;

    for (int e = grp; e < NE; e += ngrp) {
        int s = src[e], d = dst[e];
        ushort8_t gs = *(const ushort8_t*)(Gs + (size_t)s * F + c);
        ushort8_t gd = *(const ushort8_t*)(Gd + (size_t)d * F + c);
        float e0 = ea[(size_t)e * 3 + 0];
        float e1 = ea[(size_t)e * 3 + 1];
        float e2 = ea[(size_t)e * 3 + 2];

        float p = 0.f;
#pragma unroll
        for (int k = 0; k < 8; ++k) {
            float h = b2f(gs[k]) + b2f(gd[k]) + e0 * w0[k] + e1 * w1[k] + e2 * w2[k] + bb[k];
            h = fmaxf(h, 0.f);
            p += h * wc[k];
        }
#pragma unroll
        for (int off = 8; off > 0; off >>= 1) p += __shfl_down(p, off, 16);
        if (lane == 0) out[e] = p + bout;
    }
}

// ---------------------------------------------------------------------------
extern "C" void kernel_launch(void* const* d_in, const int* in_sizes, int n_in,
                              void* d_out, int out_size, void* d_ws, size_t ws_size,
                              hipStream_t stream) {
    const float* x    = (const float*)d_in[0];
    const void*  ei   = d_in[1];
    const float* ea   = (const float*)d_in[2];
    const float* W1l  = (const float*)d_in[3];
    const float* b1l  = (const float*)d_in[4];
    const float* W1r  = (const float*)d_in[5];
    const float* W2l  = (const float*)d_in[6];
    const float* b2l  = (const float*)d_in[7];
    const float* W2r  = (const float*)d_in[8];
    const float* Wc1  = (const float*)d_in[9];
    const float* bc1  = (const float*)d_in[10];
    const float* Wc2  = (const float*)d_in[11];
    const float* bc2  = (const float*)d_in[12];
    float* out = (float*)d_out;

    char* w = (char*)d_ws;
    int* flag   = (int*)w;          w += 256;
    int* bsum   = (int*)w;          w += 1024;
    int* boff   = (int*)w;          w += 1024;
    int* src    = (int*)w;          w += (size_t)NE * 4;
    int* dst    = (int*)w;          w += (size_t)NE * 4;
    int* ssort  = (int*)w;          w += (size_t)NE * 4;
    int* cnt    = (int*)w;          w += (size_t)NN * 4;
    int* rowptr = (int*)w;          w += (size_t)(NN + 1) * 4;
    int* fill   = (int*)w;          w += (size_t)NN * 4;
    w = (char*)(((size_t)w + 255) & ~(size_t)255);
    unsigned short* w1hi = (unsigned short*)w;  w += 128 * 256 * 2;
    unsigned short* w1lo = (unsigned short*)w;  w += 128 * 256 * 2;
    unsigned short* w2hi = (unsigned short*)w;  w += 128 * 256 * 2;
    unsigned short* w2lo = (unsigned short*)w;  w += 128 * 256 * 2;
    unsigned short* wchi = (unsigned short*)w;  w += 256 * 128 * 2;
    unsigned short* wclo = (unsigned short*)w;  w += 256 * 128 * 2;
    unsigned short* xh   = (unsigned short*)w;  w += (size_t)NN * F * 2;
    unsigned short* aggh = (unsigned short*)w;  w += (size_t)NN * F * 2;  // agg1, agg2
    unsigned short* h1h  = (unsigned short*)w;  w += (size_t)NN * F * 2;
    unsigned short* h2h  = (unsigned short*)w;  w += (size_t)NN * F * 2;
    unsigned short* Gsh  = (unsigned short*)w;  w += (size_t)NN * F * 2;
    unsigned short* Gdh  = (unsigned short*)w;  w += (size_t)NN * F * 2;

    hipMemsetAsync(cnt, 0, (size_t)NN * 4, stream);

    // edge-index normalization + degree histogram + casts + weight prep
    k_detect<<<1, 256, 0, stream>>>((const unsigned int*)ei, flag);
    k_convert<<<(NE + 255) / 256, 256, 0, stream>>>(ei, flag, src, dst, cnt);
    k_cast<<<(NN * F / 4 + 255) / 256, 256, 0, stream>>>(x, xh, NN * F / 4);
    k_prepw_conv<<<128, 256, 0, stream>>>(W1l, W1r, w1hi, w1lo);
    k_prepw_conv<<<128, 256, 0, stream>>>(W2l, W2r, w2hi, w2lo);
    k_prepw_cls<<<128, 256, 0, stream>>>(Wc1, wchi, wclo);

    // CSR build
    k_bsum<<<NBLK, 256, 0, stream>>>(cnt, bsum);
    k_bscan<<<1, 1, 0, stream>>>(bsum, boff);
    k_scan2<<<NBLK, 256, 0, stream>>>(cnt, boff, rowptr, fill);
    k_perm<<<(NE + 255) / 256, 256, 0, stream>>>(src, dst, fill, ssort);

    const int mmBlocks = 1024;            // 4096 waves
    const int nstripes = (mmBlocks * 4) / 8;  // 512: waves per n-tile (or pair)
    int agblocks = (NN + 15) / 16;

    // conv1: agg1 = mean-gather(xh); h1 = relu(agg1@W1l + x@W1r + b1l)
    k_gather<<<agblocks, 256, 0, stream>>>(xh, rowptr, ssort, aggh);
    k_mm_conv<<<mmBlocks, 256, 0, stream>>>(aggh, xh, w1hi, w1lo, b1l, h1h, 1, nstripes);

    // conv2: agg2 = mean-gather(h1); h2 = agg2@W2l + h1@W2r + b2l
    k_gather<<<agblocks, 256, 0, stream>>>(h1h, rowptr, ssort, aggh);
    k_mm_conv<<<mmBlocks, 256, 0, stream>>>(aggh, h1h, w2hi, w2lo, b2l, h2h, 0, nstripes);

    // classifier node-side precompute: [Gs|Gd] = h2 @ Wc1[0:256]
    k_mm_cls<<<mmBlocks, 256, 0, stream>>>(h2h, wchi, wclo, Gsh, Gdh, nstripes);

    // edge pass: 16 lanes per edge
    k_edge<<<4096, 256, 0, stream>>>(Gsh, Gdh, ea, src, dst,
                                     Wc1 + 256 * F, bc1, Wc2, bc2, out);
}

// Round 7
// 415.320 us; speedup vs baseline: 1.3170x; 1.0297x over previous
//
#include <hip/hip_runtime.h>

#define NN 50000
#define NE 800000
#define F 128
#define NBLK ((NN + 255) / 256)   // 196 scan blocks
#define NMT (NN / 16)             // 3125 m-tiles, exact

typedef __attribute__((ext_vector_type(4))) unsigned short ushort4_t;
typedef __attribute__((ext_vector_type(8))) unsigned short ushort8_t;
typedef __attribute__((ext_vector_type(8))) short bf16x8;
typedef __attribute__((ext_vector_type(4))) float f32x4;

#define MFMA16x16x32 __builtin_amdgcn_mfma_f32_16x16x32_bf16

__device__ __forceinline__ float b2f(unsigned short u) {
    return __uint_as_float((unsigned int)u << 16);
}
__device__ __forceinline__ unsigned short f2b(float f) {
    unsigned int u = __float_as_uint(f);
    return (unsigned short)((u + 0x7fffu + ((u >> 16) & 1u)) >> 16);
}

// ---------------------------------------------------------------------------
// dtype probe (sampled): 256 odd words zero <=> int64 layout.
// ---------------------------------------------------------------------------
__global__ void k_detect(const unsigned int* __restrict__ w, int* __restrict__ nz) {
    __shared__ int s;
    if (threadIdx.x == 0) s = 0;
    __syncthreads();
    if (w[2 * threadIdx.x + 1] != 0u) atomicAdd(&s, 1);
    __syncthreads();
    if (threadIdx.x == 0) *nz = s;
}

// normalize edge_index -> int32 src/dst, and histogram in-degree (cnt[dst]++)
__global__ void k_convert(const void* __restrict__ ei, const int* __restrict__ nz,
                          int* __restrict__ src, int* __restrict__ dst,
                          int* __restrict__ cnt) {
    int e = blockIdx.x * blockDim.x + threadIdx.x;
    if (e >= NE) return;
    int s, d;
    if (*nz == 0) {
        const long long* p = (const long long*)ei;
        s = (int)p[e];
        d = (int)p[NE + e];
    } else {
        const int* p = (const int*)ei;
        s = p[e];
        d = p[NE + e];
    }
    src[e] = s;
    dst[e] = d;
    atomicAdd(&cnt[d], 1);
}

// fp32 -> bf16 cast, float4/ushort4 per thread
__global__ void k_cast(const float* __restrict__ in, unsigned short* __restrict__ out,
                       int n4) {
    int i = blockIdx.x * blockDim.x + threadIdx.x;
    if (i >= n4) return;
    float4 v = ((const float4*)in)[i];
    ushort4_t o;
    o.x = f2b(v.x); o.y = f2b(v.y); o.z = f2b(v.z); o.w = f2b(v.w);
    ((ushort4_t*)out)[i] = o;
}

// ---------------------------------------------------------------------------
// Weight prep: transpose + bf16 hi/lo split (W stays exact as hi+lo).
// ---------------------------------------------------------------------------
__global__ void k_prepw_conv(const float* __restrict__ WA, const float* __restrict__ WB,
                             unsigned short* __restrict__ hi,
                             unsigned short* __restrict__ lo) {
    int i = blockIdx.x * 256 + threadIdx.x;
    if (i >= 128 * 256) return;
    int n = i >> 8, k = i & 255;
    float v = (k < 128) ? WA[(size_t)k * F + n] : WB[(size_t)(k - 128) * F + n];
    unsigned short h = f2b(v);
    hi[(size_t)n * 256 + k] = h;
    lo[(size_t)n * 256 + k] = f2b(v - b2f(h));
}

__global__ void k_prepw_cls(const float* __restrict__ Wc1,
                            unsigned short* __restrict__ hi,
                            unsigned short* __restrict__ lo) {
    int i = blockIdx.x * 256 + threadIdx.x;
    if (i >= 256 * 128) return;
    int n = i >> 7, k = i & 127;
    float v = (n < 128) ? Wc1[(size_t)k * F + n]
                        : Wc1[(size_t)(128 + k) * F + (n - 128)];
    unsigned short h = f2b(v);
    hi[(size_t)n * 128 + k] = h;
    lo[(size_t)n * 128 + k] = f2b(v - b2f(h));
}

// ---- exclusive scan of cnt[NN] -> rowptr[NN+1], plus working copy fill[]
__global__ void k_bsum(const int* __restrict__ cnt, int* __restrict__ bsum) {
    __shared__ int s[256];
    int i = blockIdx.x * 256 + threadIdx.x;
    s[threadIdx.x] = (i < NN) ? cnt[i] : 0;
    __syncthreads();
    for (int st = 128; st > 0; st >>= 1) {
        if (threadIdx.x < st) s[threadIdx.x] += s[threadIdx.x + st];
        __syncthreads();
    }
    if (threadIdx.x == 0) bsum[blockIdx.x] = s[0];
}

// single-block exclusive scan of bsum[NBLK] (replaces 1-thread serial loop)
__global__ void k_bscan(const int* __restrict__ bsum, int* __restrict__ boff) {
    __shared__ int s[256];
    int v = (threadIdx.x < NBLK) ? bsum[threadIdx.x] : 0;
    s[threadIdx.x] = v;
    __syncthreads();
    for (int st = 1; st < 256; st <<= 1) {
        int t = (threadIdx.x >= st) ? s[threadIdx.x - st] : 0;
        __syncthreads();
        s[threadIdx.x] += t;
        __syncthreads();
    }
    if (threadIdx.x < NBLK) boff[threadIdx.x] = s[threadIdx.x] - v;
}

__global__ void k_scan2(const int* __restrict__ cnt, const int* __restrict__ boff,
                        int* __restrict__ rowptr, int* __restrict__ fill) {
    __shared__ int s[256];
    int i = blockIdx.x * 256 + threadIdx.x;
    int v = (i < NN) ? cnt[i] : 0;
    s[threadIdx.x] = v;
    __syncthreads();
    for (int st = 1; st < 256; st <<= 1) {
        int t = (threadIdx.x >= st) ? s[threadIdx.x - st] : 0;
        __syncthreads();
        s[threadIdx.x] += t;
        __syncthreads();
    }
    int excl = s[threadIdx.x] - v + boff[blockIdx.x];
    if (i < NN) { rowptr[i] = excl; fill[i] = excl; }
    if (i == NN - 1) rowptr[NN] = excl + v;
}

// counting-sort edges by dst: ssort/dsort/easort; easort.w carries eid bits
__global__ void k_perm(const int* __restrict__ src, const int* __restrict__ dst,
                       const float* __restrict__ ea, int* __restrict__ fill,
                       int* __restrict__ ssort, int* __restrict__ dsort,
                       float4* __restrict__ easort) {
    int e = blockIdx.x * 256 + threadIdx.x;
    if (e >= NE) return;
    int d = dst[e];
    int pos = atomicAdd(&fill[d], 1);
    ssort[pos] = src[e];
    dsort[pos] = d;
    float4 v;
    v.x = ea[(size_t)e * 3 + 0];
    v.y = ea[(size_t)e * 3 + 1];
    v.z = ea[(size_t)e * 3 + 2];
    v.w = __int_as_float(e);
    easort[pos] = v;
}

// gather-reduce + mean over bf16 rows -> bf16 out. 16 lanes/node, 8 ch/lane.
// Run loop unrolled x4 for memory-level parallelism (row loads independent).
__launch_bounds__(256)
__global__ void k_gather(const unsigned short* __restrict__ xin,
                         const int* __restrict__ rowptr,
                         const int* __restrict__ ssort,
                         unsigned short* __restrict__ agg) {
    int n = blockIdx.x * 16 + (threadIdx.x >> 4);
    if (n >= NN) return;
    int c = (threadIdx.x & 15) << 3;
    int beg = rowptr[n], end = rowptr[n + 1];
    float acc[8] = {};
    int j = beg;
    for (; j + 4 <= end; j += 4) {
        int s0 = ssort[j], s1 = ssort[j + 1], s2 = ssort[j + 2], s3 = ssort[j + 3];
        ushort8_t v0 = *(const ushort8_t*)(xin + (size_t)s0 * F + c);
        ushort8_t v1 = *(const ushort8_t*)(xin + (size_t)s1 * F + c);
        ushort8_t v2 = *(const ushort8_t*)(xin + (size_t)s2 * F + c);
        ushort8_t v3 = *(const ushort8_t*)(xin + (size_t)s3 * F + c);
#pragma unroll
        for (int k = 0; k < 8; ++k)
            acc[k] += (b2f(v0[k]) + b2f(v1[k])) + (b2f(v2[k]) + b2f(v3[k]));
    }
    for (; j < end; ++j) {
        int s = ssort[j];
        ushort8_t v = *(const ushort8_t*)(xin + (size_t)s * F + c);
#pragma unroll
        for (int k = 0; k < 8; ++k) acc[k] += b2f(v[k]);
    }
    float sc = 1.0f / (float)max(end - beg, 1);
    ushort8_t o;
#pragma unroll
    for (int k = 0; k < 8; ++k) o[k] = f2b(acc[k] * sc);
    *(ushort8_t*)(agg + (size_t)n * F + c) = o;
}

// ---------------------------------------------------------------------------
// Conv GEMM, W-in-registers (bf16 data, W exact as hi+lo, dual acc chains).
// ---------------------------------------------------------------------------
__launch_bounds__(256)
__global__ void k_mm_conv(const unsigned short* __restrict__ A1,
                          const unsigned short* __restrict__ A2,
                          const unsigned short* __restrict__ Whi,
                          const unsigned short* __restrict__ Wlo,
                          const float* __restrict__ bias,
                          unsigned short* __restrict__ Ch,
                          int relu, int nstripes) {
    int lane = threadIdx.x & 63;
    int wid = (blockIdx.x * 256 + threadIdx.x) >> 6;
    int ntile = wid & 7;
    int stripe = wid >> 3;
    int lm = lane & 15, quad = lane >> 4;

    const unsigned short* whp = Whi + (size_t)(ntile * 16 + lm) * 256 + quad * 8;
    const unsigned short* wlp = Wlo + (size_t)(ntile * 16 + lm) * 256 + quad * 8;
    bf16x8 wh[8], wl[8];
#pragma unroll
    for (int kc = 0; kc < 8; ++kc) {
        wh[kc] = *(const bf16x8*)(whp + kc * 32);
        wl[kc] = *(const bf16x8*)(wlp + kc * 32);
    }
    int nc = ntile * 16 + quad * 4;
    f32x4 bfrag = *(const f32x4*)(bias + nc);

    for (int mt = stripe; mt < NMT; mt += nstripes) {
        int m = mt * 16 + lm;
        const unsigned short* a1p = A1 + (size_t)m * F + quad * 8;
        const unsigned short* a2p = A2 + (size_t)m * F + quad * 8;
        f32x4 accH = {0.f, 0.f, 0.f, 0.f};
        f32x4 accL = {0.f, 0.f, 0.f, 0.f};
#pragma unroll
        for (int kc = 0; kc < 4; ++kc) {
            bf16x8 d = *(const bf16x8*)(a1p + kc * 32);
            accH = MFMA16x16x32(wh[kc], d, accH, 0, 0, 0);
            accL = MFMA16x16x32(wl[kc], d, accL, 0, 0, 0);
        }
#pragma unroll
        for (int kc = 0; kc < 4; ++kc) {
            bf16x8 d = *(const bf16x8*)(a2p + kc * 32);
            accH = MFMA16x16x32(wh[4 + kc], d, accH, 0, 0, 0);
            accL = MFMA16x16x32(wl[4 + kc], d, accL, 0, 0, 0);
        }
        ushort4_t u;
#pragma unroll
        for (int r = 0; r < 4; ++r) {
            float o = accH[r] + accL[r] + bfrag[r];
            if (relu) o = fmaxf(o, 0.f);
            u[r] = f2b(o);
        }
        *(ushort4_t*)(Ch + (size_t)m * F + nc) = u;
    }
}

// ---------------------------------------------------------------------------
// Classifier GEMM: [Gs|Gd] = h2 @ Wc1[0:256]; K=128, N=256.
// ---------------------------------------------------------------------------
__launch_bounds__(256)
__global__ void k_mm_cls(const unsigned short* __restrict__ A,
                         const unsigned short* __restrict__ Whi,
                         const unsigned short* __restrict__ Wlo,
                         unsigned short* __restrict__ Gs,
                         unsigned short* __restrict__ Gd, int nstripes) {
    int lane = threadIdx.x & 63;
    int wid = (blockIdx.x * 256 + threadIdx.x) >> 6;
    int p = wid & 7;
    int stripe = wid >> 3;
    int lm = lane & 15, quad = lane >> 4;

    const unsigned short* wh0p = Whi + (size_t)(p * 16 + lm) * 128 + quad * 8;
    const unsigned short* wl0p = Wlo + (size_t)(p * 16 + lm) * 128 + quad * 8;
    const unsigned short* wh1p = Whi + (size_t)((p + 8) * 16 + lm) * 128 + quad * 8;
    const unsigned short* wl1p = Wlo + (size_t)((p + 8) * 16 + lm) * 128 + quad * 8;
    bf16x8 wh0[4], wl0[4], wh1[4], wl1[4];
#pragma unroll
    for (int kc = 0; kc < 4; ++kc) {
        wh0[kc] = *(const bf16x8*)(wh0p + kc * 32);
        wl0[kc] = *(const bf16x8*)(wl0p + kc * 32);
        wh1[kc] = *(const bf16x8*)(wh1p + kc * 32);
        wl1[kc] = *(const bf16x8*)(wl1p + kc * 32);
    }
    int nc = p * 16 + quad * 4;

    for (int mt = stripe; mt < NMT; mt += nstripes) {
        int m = mt * 16 + lm;
        const unsigned short* ap = A + (size_t)m * F + quad * 8;
        f32x4 a0H = {0.f,0.f,0.f,0.f}, a0L = {0.f,0.f,0.f,0.f};
        f32x4 a1H = {0.f,0.f,0.f,0.f}, a1L = {0.f,0.f,0.f,0.f};
#pragma unroll
        for (int kc = 0; kc < 4; ++kc) {
            bf16x8 d = *(const bf16x8*)(ap + kc * 32);
            a0H = MFMA16x16x32(wh0[kc], d, a0H, 0, 0, 0);
            a0L = MFMA16x16x32(wl0[kc], d, a0L, 0, 0, 0);
            a1H = MFMA16x16x32(wh1[kc], d, a1H, 0, 0, 0);
            a1L = MFMA16x16x32(wl1[kc], d, a1L, 0, 0, 0);
        }
        ushort4_t u0, u1;
#pragma unroll
        for (int r = 0; r < 4; ++r) {
            u0[r] = f2b(a0H[r] + a0L[r]);
            u1[r] = f2b(a1H[r] + a1L[r]);
        }
        *(ushort4_t*)(Gs + (size_t)m * F + nc) = u0;
        *(ushort4_t*)(Gd + (size_t)m * F + nc) = u1;
    }
}

// ---------------------------------------------------------------------------
// edge classifier over dst-sorted edges: grid-stride, 16 lanes/edge.
// Consecutive positions share dst and map to consecutive groups in one block
// -> Gd row reads hit L1. Output scattered to out[eid] (eid in easort.w).
// ---------------------------------------------------------------------------
__launch_bounds__(256)
__global__ void k_edge(const unsigned short* __restrict__ Gs,
                       const unsigned short* __restrict__ Gd,
                       const int* __restrict__ ssort, const int* __restrict__ dsort,
                       const float4* __restrict__ easort,
                       const float* __restrict__ Wc1e,
                       const float* __restrict__ bc1, const float* __restrict__ Wc2,
                       const float* __restrict__ bc2, float* __restrict__ out) {
    int lane = threadIdx.x & 15;
    int c = lane << 3;
    float w0[8], w1[8], w2[8], bb[8], wc[8];
#pragma unroll
    for (int k = 0; k < 8; ++k) {
        w0[k] = Wc1e[0 * F + c + k];
        w1[k] = Wc1e[1 * F + c + k];
        w2[k] = Wc1e[2 * F + c + k];
        bb[k] = bc1[c + k];
        wc[k] = Wc2[c + k];
    }
    float bout = bc2[0];

    int grp = (blockIdx.x * blockDim.x + threadIdx.x) >> 4;
    int ngrp = (gridDim.x * blockDim.x) >> 4;

    for (int pos = grp; pos < NE; pos += ngrp) {
        int s = ssort[pos], d = dsort[pos];
        float4 e4 = easort[pos];
        ushort8_t gs = *(const ushort8_t*)(Gs + (size_t)s * F + c);
        ushort8_t gd = *(const ushort8_t*)(Gd + (size_t)d * F + c);

        float p = 0.f;
#pragma unroll
        for (int k = 0; k < 8; ++k) {
            float h = b2f(gs[k]) + b2f(gd[k]) + e4.x * w0[k] + e4.y * w1[k]
                    + e4.z * w2[k] + bb[k];
            h = fmaxf(h, 0.f);
            p += h * wc[k];
        }
#pragma unroll
        for (int off = 8; off > 0; off >>= 1) p += __shfl_down(p, off, 16);
        if (lane == 0) out[__float_as_int(e4.w)] = p + bout;
    }
}

// ---------------------------------------------------------------------------
extern "C" void kernel_launch(void* const* d_in, const int* in_sizes, int n_in,
                              void* d_out, int out_size, void* d_ws, size_t ws_size,
                              hipStream_t stream) {
    const float* x    = (const float*)d_in[0];
    const void*  ei   = d_in[1];
    const float* ea   = (const float*)d_in[2];
    const float* W1l  = (const float*)d_in[3];
    const float* b1l  = (const float*)d_in[4];
    const float* W1r  = (const float*)d_in[5];
    const float* W2l  = (const float*)d_in[6];
    const float* b2l  = (const float*)d_in[7];
    const float* W2r  = (const float*)d_in[8];
    const float* Wc1  = (const float*)d_in[9];
    const float* bc1  = (const float*)d_in[10];
    const float* Wc2  = (const float*)d_in[11];
    const float* bc2  = (const float*)d_in[12];
    float* out = (float*)d_out;

    char* w = (char*)d_ws;
    int* flag   = (int*)w;          w += 256;
    int* bsum   = (int*)w;          w += 1024;
    int* boff   = (int*)w;          w += 1024;
    int* src    = (int*)w;          w += (size_t)NE * 4;
    int* dst    = (int*)w;          w += (size_t)NE * 4;
    int* ssort  = (int*)w;          w += (size_t)NE * 4;
    int* dsort  = (int*)w;          w += (size_t)NE * 4;
    int* cnt    = (int*)w;          w += (size_t)NN * 4;
    int* rowptr = (int*)w;          w += (size_t)(NN + 1) * 4;
    int* fill   = (int*)w;          w += (size_t)NN * 4;
    w = (char*)(((size_t)w + 255) & ~(size_t)255);
    float4* easort = (float4*)w;                w += (size_t)NE * 16;
    unsigned short* w1hi = (unsigned short*)w;  w += 128 * 256 * 2;
    unsigned short* w1lo = (unsigned short*)w;  w += 128 * 256 * 2;
    unsigned short* w2hi = (unsigned short*)w;  w += 128 * 256 * 2;
    unsigned short* w2lo = (unsigned short*)w;  w += 128 * 256 * 2;
    unsigned short* wchi = (unsigned short*)w;  w += 256 * 128 * 2;
    unsigned short* wclo = (unsigned short*)w;  w += 256 * 128 * 2;
    unsigned short* xh   = (unsigned short*)w;  w += (size_t)NN * F * 2;
    unsigned short* aggh = (unsigned short*)w;  w += (size_t)NN * F * 2;
    unsigned short* h1h  = (unsigned short*)w;  w += (size_t)NN * F * 2;
    unsigned short* h2h  = (unsigned short*)w;  w += (size_t)NN * F * 2;
    // aliases: xh dead after conv1 GEMM; aggh dead after conv2 GEMM.
    unsigned short* Gsh = xh;
    unsigned short* Gdh = aggh;

    hipMemsetAsync(cnt, 0, (size_t)NN * 4, stream);

    // edge-index normalization + degree histogram + casts + weight prep
    k_detect<<<1, 256, 0, stream>>>((const unsigned int*)ei, flag);
    k_convert<<<(NE + 255) / 256, 256, 0, stream>>>(ei, flag, src, dst, cnt);
    k_cast<<<(NN * F / 4 + 255) / 256, 256, 0, stream>>>(x, xh, NN * F / 4);
    k_prepw_conv<<<128, 256, 0, stream>>>(W1l, W1r, w1hi, w1lo);
    k_prepw_conv<<<128, 256, 0, stream>>>(W2l, W2r, w2hi, w2lo);
    k_prepw_cls<<<128, 256, 0, stream>>>(Wc1, wchi, wclo);

    // CSR build + dst-sorted edge arrays
    k_bsum<<<NBLK, 256, 0, stream>>>(cnt, bsum);
    k_bscan<<<1, 256, 0, stream>>>(bsum, boff);
    k_scan2<<<NBLK, 256, 0, stream>>>(cnt, boff, rowptr, fill);
    k_perm<<<(NE + 255) / 256, 256, 0, stream>>>(src, dst, ea, fill,
                                                 ssort, dsort, easort);

    const int mmBlocks = 1024;
    const int nstripes = (mmBlocks * 4) / 8;  // 512
    int agblocks = (NN + 15) / 16;

    // conv1: agg1 = mean-gather(xh); h1 = relu(agg1@W1l + x@W1r + b1l)
    k_gather<<<agblocks, 256, 0, stream>>>(xh, rowptr, ssort, aggh);
    k_mm_conv<<<mmBlocks, 256, 0, stream>>>(aggh, xh, w1hi, w1lo, b1l, h1h, 1, nstripes);

    // conv2: agg2 = mean-gather(h1); h2 = agg2@W2l + h1@W2r + b2l
    k_gather<<<agblocks, 256, 0, stream>>>(h1h, rowptr, ssort, aggh);
    k_mm_conv<<<mmBlocks, 256, 0, stream>>>(aggh, h1h, w2hi, w2lo, b2l, h2h, 0, nstripes);

    // classifier node-side precompute: [Gs|Gd] = h2 @ Wc1[0:256]
    k_mm_cls<<<mmBlocks, 256, 0, stream>>>(h2h, wchi, wclo, Gsh, Gdh, nstripes);

    // edge pass over dst-sorted edges
    k_edge<<<4096, 256, 0, stream>>>(Gsh, Gdh, ssort, dsort, easort,
                                     Wc1 + 256 * F, bc1, Wc2, bc2, out);
}

// Round 8
// 390.890 us; speedup vs baseline: 1.3993x; 1.0625x over previous
//
#include <hip/hip_runtime.h>

#define NN 50000
#define NE 800000
#define F 128
#define NBLK ((NN + 255) / 256)   // 196 scan blocks
#define NMT (NN / 16)             // 3125 m-tiles, exact

typedef __attribute__((ext_vector_type(4))) unsigned short ushort4_t;
typedef __attribute__((ext_vector_type(8))) unsigned short ushort8_t;
typedef __attribute__((ext_vector_type(8))) short bf16x8;
typedef __attribute__((ext_vector_type(4))) float f32x4;

#define MFMA16x16x32 __builtin_amdgcn_mfma_f32_16x16x32_bf16

__device__ __forceinline__ float b2f(unsigned short u) {
    return __uint_as_float((unsigned int)u << 16);
}
__device__ __forceinline__ unsigned short f2b(float f) {
    unsigned int u = __float_as_uint(f);
    return (unsigned short)((u + 0x7fffu + ((u >> 16) & 1u)) >> 16);
}

// ---------------------------------------------------------------------------
// dtype probe (sampled): 256 odd words zero <=> int64 layout.
// ---------------------------------------------------------------------------
__global__ void k_detect(const unsigned int* __restrict__ w, int* __restrict__ nz) {
    __shared__ int s;
    if (threadIdx.x == 0) s = 0;
    __syncthreads();
    if (w[2 * threadIdx.x + 1] != 0u) atomicAdd(&s, 1);
    __syncthreads();
    if (threadIdx.x == 0) *nz = s;
}

// normalize edge_index -> int32 src/dst, and histogram in-degree (cnt[dst]++)
__global__ void k_convert(const void* __restrict__ ei, const int* __restrict__ nz,
                          int* __restrict__ src, int* __restrict__ dst,
                          int* __restrict__ cnt) {
    int e = blockIdx.x * blockDim.x + threadIdx.x;
    if (e >= NE) return;
    int s, d;
    if (*nz == 0) {
        const long long* p = (const long long*)ei;
        s = (int)p[e];
        d = (int)p[NE + e];
    } else {
        const int* p = (const int*)ei;
        s = p[e];
        d = p[NE + e];
    }
    src[e] = s;
    dst[e] = d;
    atomicAdd(&cnt[d], 1);
}

// ---------------------------------------------------------------------------
// Fused prep: bf16 cast of x (blocks 0..6249), W1 prep (6250..6377),
// W2 prep (6378..6505), Wc1 prep (6506..6633). All independent.
// ---------------------------------------------------------------------------
__device__ __forceinline__ void prepw_conv_body(int i, const float* __restrict__ WA,
                                                const float* __restrict__ WB,
                                                unsigned short* __restrict__ hi,
                                                unsigned short* __restrict__ lo) {
    int n = i >> 8, k = i & 255;
    float v = (k < 128) ? WA[(size_t)k * F + n] : WB[(size_t)(k - 128) * F + n];
    unsigned short h = f2b(v);
    hi[(size_t)n * 256 + k] = h;
    lo[(size_t)n * 256 + k] = f2b(v - b2f(h));
}

__global__ void k_prep(const float* __restrict__ x, unsigned short* __restrict__ xh,
                       const float* __restrict__ W1l, const float* __restrict__ W1r,
                       unsigned short* __restrict__ w1hi, unsigned short* __restrict__ w1lo,
                       const float* __restrict__ W2l, const float* __restrict__ W2r,
                       unsigned short* __restrict__ w2hi, unsigned short* __restrict__ w2lo,
                       const float* __restrict__ Wc1,
                       unsigned short* __restrict__ wchi, unsigned short* __restrict__ wclo) {
    int b = blockIdx.x;
    if (b < 6250) {                       // cast: NN*F/4 = 1.6M float4 groups
        int i = b * 256 + threadIdx.x;
        float4 v = ((const float4*)x)[i];
        ushort4_t o;
        o.x = f2b(v.x); o.y = f2b(v.y); o.z = f2b(v.z); o.w = f2b(v.w);
        ((ushort4_t*)xh)[i] = o;
    } else if (b < 6378) {
        prepw_conv_body((b - 6250) * 256 + threadIdx.x, W1l, W1r, w1hi, w1lo);
    } else if (b < 6506) {
        prepw_conv_body((b - 6378) * 256 + threadIdx.x, W2l, W2r, w2hi, w2lo);
    } else {
        int i = (b - 6506) * 256 + threadIdx.x;
        int n = i >> 7, k = i & 127;
        float v = (n < 128) ? Wc1[(size_t)k * F + n]
                            : Wc1[(size_t)(128 + k) * F + (n - 128)];
        unsigned short h = f2b(v);
        wchi[(size_t)n * 128 + k] = h;
        wclo[(size_t)n * 128 + k] = f2b(v - b2f(h));
    }
}

// ---- exclusive scan of cnt[NN] -> rowptr[NN+1], plus working copy fill[]
__global__ void k_bsum(const int* __restrict__ cnt, int* __restrict__ bsum) {
    __shared__ int s[256];
    int i = blockIdx.x * 256 + threadIdx.x;
    s[threadIdx.x] = (i < NN) ? cnt[i] : 0;
    __syncthreads();
    for (int st = 128; st > 0; st >>= 1) {
        if (threadIdx.x < st) s[threadIdx.x] += s[threadIdx.x + st];
        __syncthreads();
    }
    if (threadIdx.x == 0) bsum[blockIdx.x] = s[0];
}

__global__ void k_bscan(const int* __restrict__ bsum, int* __restrict__ boff) {
    __shared__ int s[256];
    int v = (threadIdx.x < NBLK) ? bsum[threadIdx.x] : 0;
    s[threadIdx.x] = v;
    __syncthreads();
    for (int st = 1; st < 256; st <<= 1) {
        int t = (threadIdx.x >= st) ? s[threadIdx.x - st] : 0;
        __syncthreads();
        s[threadIdx.x] += t;
        __syncthreads();
    }
    if (threadIdx.x < NBLK) boff[threadIdx.x] = s[threadIdx.x] - v;
}

__global__ void k_scan2(const int* __restrict__ cnt, const int* __restrict__ boff,
                        int* __restrict__ rowptr, int* __restrict__ fill) {
    __shared__ int s[256];
    int i = blockIdx.x * 256 + threadIdx.x;
    int v = (i < NN) ? cnt[i] : 0;
    s[threadIdx.x] = v;
    __syncthreads();
    for (int st = 1; st < 256; st <<= 1) {
        int t = (threadIdx.x >= st) ? s[threadIdx.x - st] : 0;
        __syncthreads();
        s[threadIdx.x] += t;
        __syncthreads();
    }
    int excl = s[threadIdx.x] - v + boff[blockIdx.x];
    if (i < NN) { rowptr[i] = excl; fill[i] = excl; }
    if (i == NN - 1) rowptr[NN] = excl + v;
}

// counting-sort edges by dst: ssort/dsort/easort; easort.w carries eid bits
__global__ void k_perm(const int* __restrict__ src, const int* __restrict__ dst,
                       const float* __restrict__ ea, int* __restrict__ fill,
                       int* __restrict__ ssort, int* __restrict__ dsort,
                       float4* __restrict__ easort) {
    int e = blockIdx.x * 256 + threadIdx.x;
    if (e >= NE) return;
    int d = dst[e];
    int pos = atomicAdd(&fill[d], 1);
    ssort[pos] = src[e];
    dsort[pos] = d;
    float4 v;
    v.x = ea[(size_t)e * 3 + 0];
    v.y = ea[(size_t)e * 3 + 1];
    v.z = ea[(size_t)e * 3 + 2];
    v.w = __int_as_float(e);
    easort[pos] = v;
}

// gather-reduce + mean over bf16 rows -> bf16 out. 16 lanes/node, 8 ch/lane.
__launch_bounds__(256)
__global__ void k_gather(const unsigned short* __restrict__ xin,
                         const int* __restrict__ rowptr,
                         const int* __restrict__ ssort,
                         unsigned short* __restrict__ agg) {
    int n = blockIdx.x * 16 + (threadIdx.x >> 4);
    if (n >= NN) return;
    int c = (threadIdx.x & 15) << 3;
    int beg = rowptr[n], end = rowptr[n + 1];
    float acc[8] = {};
    int j = beg;
    for (; j + 4 <= end; j += 4) {
        int s0 = ssort[j], s1 = ssort[j + 1], s2 = ssort[j + 2], s3 = ssort[j + 3];
        ushort8_t v0 = *(const ushort8_t*)(xin + (size_t)s0 * F + c);
        ushort8_t v1 = *(const ushort8_t*)(xin + (size_t)s1 * F + c);
        ushort8_t v2 = *(const ushort8_t*)(xin + (size_t)s2 * F + c);
        ushort8_t v3 = *(const ushort8_t*)(xin + (size_t)s3 * F + c);
#pragma unroll
        for (int k = 0; k < 8; ++k)
            acc[k] += (b2f(v0[k]) + b2f(v1[k])) + (b2f(v2[k]) + b2f(v3[k]));
    }
    for (; j < end; ++j) {
        int s = ssort[j];
        ushort8_t v = *(const ushort8_t*)(xin + (size_t)s * F + c);
#pragma unroll
        for (int k = 0; k < 8; ++k) acc[k] += b2f(v[k]);
    }
    float sc = 1.0f / (float)max(end - beg, 1);
    ushort8_t o;
#pragma unroll
    for (int k = 0; k < 8; ++k) o[k] = f2b(acc[k] * sc);
    *(ushort8_t*)(agg + (size_t)n * F + c) = o;
}

// ---------------------------------------------------------------------------
// Conv GEMM, W-in-registers (bf16 data, W exact as hi+lo, dual acc chains).
// ---------------------------------------------------------------------------
__launch_bounds__(256)
__global__ void k_mm_conv(const unsigned short* __restrict__ A1,
                          const unsigned short* __restrict__ A2,
                          const unsigned short* __restrict__ Whi,
                          const unsigned short* __restrict__ Wlo,
                          const float* __restrict__ bias,
                          unsigned short* __restrict__ Ch,
                          int relu, int nstripes) {
    int lane = threadIdx.x & 63;
    int wid = (blockIdx.x * 256 + threadIdx.x) >> 6;
    int ntile = wid & 7;
    int stripe = wid >> 3;
    int lm = lane & 15, quad = lane >> 4;

    const unsigned short* whp = Whi + (size_t)(ntile * 16 + lm) * 256 + quad * 8;
    const unsigned short* wlp = Wlo + (size_t)(ntile * 16 + lm) * 256 + quad * 8;
    bf16x8 wh[8], wl[8];
#pragma unroll
    for (int kc = 0; kc < 8; ++kc) {
        wh[kc] = *(const bf16x8*)(whp + kc * 32);
        wl[kc] = *(const bf16x8*)(wlp + kc * 32);
    }
    int nc = ntile * 16 + quad * 4;
    f32x4 bfrag = *(const f32x4*)(bias + nc);

    for (int mt = stripe; mt < NMT; mt += nstripes) {
        int m = mt * 16 + lm;
        const unsigned short* a1p = A1 + (size_t)m * F + quad * 8;
        const unsigned short* a2p = A2 + (size_t)m * F + quad * 8;
        f32x4 accH = {0.f, 0.f, 0.f, 0.f};
        f32x4 accL = {0.f, 0.f, 0.f, 0.f};
#pragma unroll
        for (int kc = 0; kc < 4; ++kc) {
            bf16x8 d = *(const bf16x8*)(a1p + kc * 32);
            accH = MFMA16x16x32(wh[kc], d, accH, 0, 0, 0);
            accL = MFMA16x16x32(wl[kc], d, accL, 0, 0, 0);
        }
#pragma unroll
        for (int kc = 0; kc < 4; ++kc) {
            bf16x8 d = *(const bf16x8*)(a2p + kc * 32);
            accH = MFMA16x16x32(wh[4 + kc], d, accH, 0, 0, 0);
            accL = MFMA16x16x32(wl[4 + kc], d, accL, 0, 0, 0);
        }
        ushort4_t u;
#pragma unroll
        for (int r = 0; r < 4; ++r) {
            float o = accH[r] + accL[r] + bfrag[r];
            if (relu) o = fmaxf(o, 0.f);
            u[r] = f2b(o);
        }
        *(ushort4_t*)(Ch + (size_t)m * F + nc) = u;
    }
}

// ---------------------------------------------------------------------------
// Classifier GEMM: [Gs|Gd] = h2 @ Wc1[0:256]; K=128, N=256.
// ---------------------------------------------------------------------------
__launch_bounds__(256)
__global__ void k_mm_cls(const unsigned short* __restrict__ A,
                         const unsigned short* __restrict__ Whi,
                         const unsigned short* __restrict__ Wlo,
                         unsigned short* __restrict__ Gs,
                         unsigned short* __restrict__ Gd, int nstripes) {
    int lane = threadIdx.x & 63;
    int wid = (blockIdx.x * 256 + threadIdx.x) >> 6;
    int p = wid & 7;
    int stripe = wid >> 3;
    int lm = lane & 15, quad = lane >> 4;

    const unsigned short* wh0p = Whi + (size_t)(p * 16 + lm) * 128 + quad * 8;
    const unsigned short* wl0p = Wlo + (size_t)(p * 16 + lm) * 128 + quad * 8;
    const unsigned short* wh1p = Whi + (size_t)((p + 8) * 16 + lm) * 128 + quad * 8;
    const unsigned short* wl1p = Wlo + (size_t)((p + 8) * 16 + lm) * 128 + quad * 8;
    bf16x8 wh0[4], wl0[4], wh1[4], wl1[4];
#pragma unroll
    for (int kc = 0; kc < 4; ++kc) {
        wh0[kc] = *(const bf16x8*)(wh0p + kc * 32);
        wl0[kc] = *(const bf16x8*)(wl0p + kc * 32);
        wh1[kc] = *(const bf16x8*)(wh1p + kc * 32);
        wl1[kc] = *(const bf16x8*)(wl1p + kc * 32);
    }
    int nc = p * 16 + quad * 4;

    for (int mt = stripe; mt < NMT; mt += nstripes) {
        int m = mt * 16 + lm;
        const unsigned short* ap = A + (size_t)m * F + quad * 8;
        f32x4 a0H = {0.f,0.f,0.f,0.f}, a0L = {0.f,0.f,0.f,0.f};
        f32x4 a1H = {0.f,0.f,0.f,0.f}, a1L = {0.f,0.f,0.f,0.f};
#pragma unroll
        for (int kc = 0; kc < 4; ++kc) {
            bf16x8 d = *(const bf16x8*)(ap + kc * 32);
            a0H = MFMA16x16x32(wh0[kc], d, a0H, 0, 0, 0);
            a0L = MFMA16x16x32(wl0[kc], d, a0L, 0, 0, 0);
            a1H = MFMA16x16x32(wh1[kc], d, a1H, 0, 0, 0);
            a1L = MFMA16x16x32(wl1[kc], d, a1L, 0, 0, 0);
        }
        ushort4_t u0, u1;
#pragma unroll
        for (int r = 0; r < 4; ++r) {
            u0[r] = f2b(a0H[r] + a0L[r]);
            u1[r] = f2b(a1H[r] + a1L[r]);
        }
        *(ushort4_t*)(Gs + (size_t)m * F + nc) = u0;
        *(ushort4_t*)(Gd + (size_t)m * F + nc) = u1;
    }
}

// ---------------------------------------------------------------------------
// edge classifier over dst-sorted edges: 16 lanes/edge, TWO edges per group
// per iteration (independent loads + MLP chains -> latency hiding).
// NE is even and all strides are even, so pos+1 is always valid.
// ---------------------------------------------------------------------------
__launch_bounds__(256)
__global__ void k_edge(const unsigned short* __restrict__ Gs,
                       const unsigned short* __restrict__ Gd,
                       const int* __restrict__ ssort, const int* __restrict__ dsort,
                       const float4* __restrict__ easort,
                       const float* __restrict__ Wc1e,
                       const float* __restrict__ bc1, const float* __restrict__ Wc2,
                       const float* __restrict__ bc2, float* __restrict__ out) {
    int lane = threadIdx.x & 15;
    int c = lane << 3;
    float w0[8], w1[8], w2[8], bb[8], wc[8];
#pragma unroll
    for (int k = 0; k < 8; ++k) {
        w0[k] = Wc1e[0 * F + c + k];
        w1[k] = Wc1e[1 * F + c + k];
        w2[k] = Wc1e[2 * F + c + k];
        bb[k] = bc1[c + k];
        wc[k] = Wc2[c + k];
    }
    float bout = bc2[0];

    int grp = (blockIdx.x * blockDim.x + threadIdx.x) >> 4;
    int ngrp = (gridDim.x * blockDim.x) >> 4;

    for (int pos = grp * 2; pos < NE; pos += ngrp * 2) {
        int s0 = ssort[pos],     d0 = dsort[pos];
        int s1 = ssort[pos + 1], d1 = dsort[pos + 1];
        float4 e40 = easort[pos];
        float4 e41 = easort[pos + 1];
        ushort8_t gs0 = *(const ushort8_t*)(Gs + (size_t)s0 * F + c);
        ushort8_t gd0 = *(const ushort8_t*)(Gd + (size_t)d0 * F + c);
        ushort8_t gs1 = *(const ushort8_t*)(Gs + (size_t)s1 * F + c);
        ushort8_t gd1 = *(const ushort8_t*)(Gd + (size_t)d1 * F + c);

        float p0 = 0.f, p1 = 0.f;
#pragma unroll
        for (int k = 0; k < 8; ++k) {
            float h0 = b2f(gs0[k]) + b2f(gd0[k]) + e40.x * w0[k] + e40.y * w1[k]
                     + e40.z * w2[k] + bb[k];
            float h1 = b2f(gs1[k]) + b2f(gd1[k]) + e41.x * w0[k] + e41.y * w1[k]
                     + e41.z * w2[k] + bb[k];
            p0 += fmaxf(h0, 0.f) * wc[k];
            p1 += fmaxf(h1, 0.f) * wc[k];
        }
#pragma unroll
        for (int off = 8; off > 0; off >>= 1) {
            p0 += __shfl_down(p0, off, 16);
            p1 += __shfl_down(p1, off, 16);
        }
        if (lane == 0) {
            out[__float_as_int(e40.w)] = p0 + bout;
            out[__float_as_int(e41.w)] = p1 + bout;
        }
    }
}

// ---------------------------------------------------------------------------
extern "C" void kernel_launch(void* const* d_in, const int* in_sizes, int n_in,
                              void* d_out, int out_size, void* d_ws, size_t ws_size,
                              hipStream_t stream) {
    const float* x    = (const float*)d_in[0];
    const void*  ei   = d_in[1];
    const float* ea   = (const float*)d_in[2];
    const float* W1l  = (const float*)d_in[3];
    const float* b1l  = (const float*)d_in[4];
    const float* W1r  = (const float*)d_in[5];
    const float* W2l  = (const float*)d_in[6];
    const float* b2l  = (const float*)d_in[7];
    const float* W2r  = (const float*)d_in[8];
    const float* Wc1  = (const float*)d_in[9];
    const float* bc1  = (const float*)d_in[10];
    const float* Wc2  = (const float*)d_in[11];
    const float* bc2  = (const float*)d_in[12];
    float* out = (float*)d_out;

    char* w = (char*)d_ws;
    int* flag   = (int*)w;          w += 256;
    int* bsum   = (int*)w;          w += 1024;
    int* boff   = (int*)w;          w += 1024;
    int* src    = (int*)w;          w += (size_t)NE * 4;
    int* dst    = (int*)w;          w += (size_t)NE * 4;
    int* ssort  = (int*)w;          w += (size_t)NE * 4;
    int* dsort  = (int*)w;          w += (size_t)NE * 4;
    int* cnt    = (int*)w;          w += (size_t)NN * 4;
    int* rowptr = (int*)w;          w += (size_t)(NN + 1) * 4;
    int* fill   = (int*)w;          w += (size_t)NN * 4;
    w = (char*)(((size_t)w + 255) & ~(size_t)255);
    float4* easort = (float4*)w;                w += (size_t)NE * 16;
    unsigned short* w1hi = (unsigned short*)w;  w += 128 * 256 * 2;
    unsigned short* w1lo = (unsigned short*)w;  w += 128 * 256 * 2;
    unsigned short* w2hi = (unsigned short*)w;  w += 128 * 256 * 2;
    unsigned short* w2lo = (unsigned short*)w;  w += 128 * 256 * 2;
    unsigned short* wchi = (unsigned short*)w;  w += 256 * 128 * 2;
    unsigned short* wclo = (unsigned short*)w;  w += 256 * 128 * 2;
    unsigned short* xh   = (unsigned short*)w;  w += (size_t)NN * F * 2;
    unsigned short* aggh = (unsigned short*)w;  w += (size_t)NN * F * 2;
    unsigned short* h1h  = (unsigned short*)w;  w += (size_t)NN * F * 2;
    unsigned short* h2h  = (unsigned short*)w;  w += (size_t)NN * F * 2;
    // aliases: xh dead after conv1 GEMM; aggh dead after conv2 GEMM.
    unsigned short* Gsh = xh;
    unsigned short* Gdh = aggh;

    hipMemsetAsync(cnt, 0, (size_t)NN * 4, stream);

    // edge-index normalization + degree histogram + fused casts/weight prep
    k_detect<<<1, 256, 0, stream>>>((const unsigned int*)ei, flag);
    k_convert<<<(NE + 255) / 256, 256, 0, stream>>>(ei, flag, src, dst, cnt);
    k_prep<<<6634, 256, 0, stream>>>(x, xh, W1l, W1r, w1hi, w1lo,
                                     W2l, W2r, w2hi, w2lo, Wc1, wchi, wclo);

    // CSR build + dst-sorted edge arrays
    k_bsum<<<NBLK, 256, 0, stream>>>(cnt, bsum);
    k_bscan<<<1, 256, 0, stream>>>(bsum, boff);
    k_scan2<<<NBLK, 256, 0, stream>>>(cnt, boff, rowptr, fill);
    k_perm<<<(NE + 255) / 256, 256, 0, stream>>>(src, dst, ea, fill,
                                                 ssort, dsort, easort);

    const int mmBlocks = 1024;
    const int nstripes = (mmBlocks * 4) / 8;  // 512
    int agblocks = (NN + 15) / 16;

    // conv1: agg1 = mean-gather(xh); h1 = relu(agg1@W1l + x@W1r + b1l)
    k_gather<<<agblocks, 256, 0, stream>>>(xh, rowptr, ssort, aggh);
    k_mm_conv<<<mmBlocks, 256, 0, stream>>>(aggh, xh, w1hi, w1lo, b1l, h1h, 1, nstripes);

    // conv2: agg2 = mean-gather(h1); h2 = agg2@W2l + h1@W2r + b2l
    k_gather<<<agblocks, 256, 0, stream>>>(h1h, rowptr, ssort, aggh);
    k_mm_conv<<<mmBlocks, 256, 0, stream>>>(aggh, h1h, w2hi, w2lo, b2l, h2h, 0, nstripes);

    // classifier node-side precompute: [Gs|Gd] = h2 @ Wc1[0:256]
    k_mm_cls<<<mmBlocks, 256, 0, stream>>>(h2h, wchi, wclo, Gsh, Gdh, nstripes);

    // edge pass over dst-sorted edges, 2 edges per group-iteration
    k_edge<<<4096, 256, 0, stream>>>(Gsh, Gdh, ssort, dsort, easort,
                                     Wc1 + 256 * F, bc1, Wc2, bc2, out);
}